// Round 5
// baseline (466.320 us; speedup 1.0000x reference)
//
#include <hip/hip_runtime.h>

#define M_DIM 8192
#define K_DIM 2048
#define N_DIM 5632

typedef __attribute__((ext_vector_type(8))) short short8;
typedef __attribute__((ext_vector_type(4))) short s4v;
typedef __attribute__((ext_vector_type(4))) float f32x4;

// fp32 -> bf16 round-to-nearest-even (bit trick; inputs are finite)
__device__ __forceinline__ short f2b(float f) {
  union { float f; unsigned u; } v; v.f = f;
  unsigned r = v.u + 0x7FFFu + ((v.u >> 16) & 1u);
  return (short)(r >> 16);
}

// async global->LDS, 16B per lane. LDS dest must be wave-uniform base + lane*16.
__device__ __forceinline__ void async16(void* lds, const void* g) {
  __builtin_amdgcn_global_load_lds(
      (const __attribute__((address_space(1))) unsigned*)g,
      (__attribute__((address_space(3))) unsigned*)lds,
      16, 0, 0);
}

// ---------------- Kernel 1: x fp32 -> bf16 (fully coalesced) -----------------
__global__ __launch_bounds__(256) void cvt_x_kernel(const float* __restrict__ x,
                                                    short* __restrict__ xb) {
  long t = (long)blockIdx.x * 256 + threadIdx.x;   // 4 elements per thread
  float4 f = ((const float4*)x)[t];
  s4v o;
  o[0] = f2b(f.x); o[1] = f2b(f.y); o[2] = f2b(f.z); o[3] = f2b(f.w);
  *(s4v*)(xb + 4 * t) = o;
}

// ---------------- Kernel 1b: transpose lA -> lAT[16][2048], fold 2x scale ----
__global__ __launch_bounds__(256) void lat_kernel(const float* __restrict__ lA,
                                                  float* __restrict__ lAT) {
  int i = blockIdx.x * 256 + threadIdx.x;          // 8 blocks x 256 = 2048
  const float4* row = (const float4*)(lA + (size_t)i * 16);
  float4 v0 = row[0], v1 = row[1], v2 = row[2], v3 = row[3];
  float vals[16] = {v0.x, v0.y, v0.z, v0.w, v1.x, v1.y, v1.z, v1.w,
                    v2.x, v2.y, v2.z, v2.w, v3.x, v3.y, v3.z, v3.w};
#pragma unroll
  for (int r = 0; r < 16; ++r) lAT[r * K_DIM + i] = vals[r] * 2.0f;
}

// ---------------- Kernel 2: dequant int4 + fold rank-16 LoRA into W' ---------
// W'[o][i] = (q - zero[g]) * scale[g] + sum_r lAT[r][i] * lB[r][o]
__global__ __launch_bounds__(256) void dequant_lora_kernel(
    const int* __restrict__ packed, const float* __restrict__ scales,
    const float* __restrict__ zeros, const float* __restrict__ lAT,
    const float* __restrict__ lB, short* __restrict__ wb) {
  int o = blockIdx.x;
  int i0 = threadIdx.x * 8;
  long e0 = (long)o * K_DIM + i0;
  int4 p = ((const int4*)packed)[e0 >> 3];
  int g = (int)(e0 >> 7);
  float s = scales[g], z = zeros[g];

  float accv[8];
#pragma unroll
  for (int d = 0; d < 4; ++d) {
    int pv = (&p.x)[d];
    accv[2 * d]     = ((float)(pv & 0xF) - z) * s;
    accv[2 * d + 1] = ((float)((pv >> 4) & 0xF) - z) * s;
  }
#pragma unroll
  for (int r = 0; r < 16; ++r) {
    float b = lB[r * N_DIM + o];             // uniform per block -> scalar load
    const float4* ar = (const float4*)&lAT[r * K_DIM + i0];
    float4 a0 = ar[0], a1 = ar[1];
    accv[0] += a0.x * b; accv[1] += a0.y * b;
    accv[2] += a0.z * b; accv[3] += a0.w * b;
    accv[4] += a1.x * b; accv[5] += a1.y * b;
    accv[6] += a1.z * b; accv[7] += a1.w * b;
  }
  short8 out8;
#pragma unroll
  for (int j = 0; j < 8; ++j) out8[j] = f2b(accv[j]);
  *(short8*)(wb + e0) = out8;
}

// ---------------- Kernel 3: C[m][n] = sum_k X[m][k] * W'[n][k] ---------------
// m201-template port. 256x256 tile, BK=64, 8 waves (2Mx4N), acc[8][4]/wave.
// LDS double-buffer: A 2x32KB + B 2x32KB = 128 KB. Each buf split into two
// k-slices (ks0: k 0..31, ks1: k 32..63), region = 256 rows x 32k, row stride
// 64B -> ds_read_b128 is bank-UNIFORM with no swizzle (16 rows x 4 chunks
// cover all 32 banks exactly 8x).
// Phase = {ds_reads; stage; BAR; lgkmcnt(0); setprio(1); 16 MFMA; setprio(0);
// [vmcnt]; BAR}. The 16-MFMA cluster = ~620 cyc of matrix-pipe backlog per
// SIMD (2 waves); it drains ACROSS the barrier, hiding the next phase's
// lgkm-wait + LDS burst. (R4's 8-MFMA phases had half the backlog ->
// serialization persisted at 2500 cyc/tile-32; m201 runs 1650 equiv.)
// 4 phases per K-tile: ph0 m0-3/ks0, ph1 m4-7/ks0, ph2 m0-3/ks1, ph3 m4-7/ks1.
// Stage of tile t+1 spread: ph0 A-ks0, ph1 B-ks0, ph2 A-ks1, ph3 B-ks1.
// Counted vmcnt(4) at end-ph1 (retires ks1(t), staged 2 phases ago) and
// end-ph3 (retires ks0(t+1)) -- never 0 in the main loop.
// Hazards: stage into buf (t+1)&1 region R issues in a phase AFTER the
// end-of-tile-(t-1) barrier, by which point every wave consumed R (data in
// regs pre-MFMA, MFMA pre-barrier). Reads of each ks gated by its vmcnt+BAR.
__global__ __launch_bounds__(512, 2) void gemm_kernel(const short* __restrict__ xb,
                                                      const short* __restrict__ wb,
                                                      float* __restrict__ out) {
  // shorts: A bufs [0, 32768), B bufs [32768, 65536). buf c: base + c*16384;
  // within buf: ks slice s at + s*8192; row r chunk q at r*32 + q*8.
  __shared__ __align__(16) short lds[65536];   // 128 KB

  const int tid = threadIdx.x;
  const int lane = tid & 63;
  const int wave = tid >> 6;
  const int wm = wave >> 2, wn = wave & 3;     // 2(M) x 4(N) wave grid
  const int l15 = lane & 15, quad = lane >> 4;

  // XCD-aware bijective swizzle: 704 blocks = 8 XCDs x 88
  int flat = blockIdx.x;
  int swz = (flat & 7) * 88 + (flat >> 3);
  int bm = swz / 22, bn_ = swz - bm * 22;
  const int m0 = bm * 256, n0 = bn_ * 256;

  const short* a_base = xb + (size_t)m0 * K_DIM;
  const short* b_base = wb + (size_t)n0 * K_DIM;

  // ds_read offsets (shorts) within a ks region
  const int a_rd = (wm * 128 + l15) * 32 + quad * 8;   // + m*512
  const int b_rd = (wn * 64 + l15) * 32 + quad * 8;    // + n*512

  // Staging addresses: thread stages chunk i=tid and i=512+tid of each 16KB
  // half (chunk i -> row i>>2, k-chunk i&3). Linear LDS dest, linear source.
  const short* ag0 = a_base + (size_t)(tid >> 2) * K_DIM + (tid & 3) * 8;
  const short* bg0 = b_base + (size_t)(tid >> 2) * K_DIM + (tid & 3) * 8;
  const int sl0 = tid * 8, sl1 = (512 + tid) * 8;

  f32x4 acc[8][4] = {};

  // stage A or B k-slice s of K-tile t into buf (t&1)
  auto stageA = [&](int t, int s) {
    const int d = (t & 1) * 16384 + s * 8192;
    const short* g = ag0 + t * 64 + s * 32;
    async16(&lds[d + sl0], g);
    async16(&lds[d + sl1], g + (size_t)128 * K_DIM);
  };
  auto stageB = [&](int t, int s) {
    const int d = 32768 + (t & 1) * 16384 + s * 8192;
    const short* g = bg0 + t * 64 + s * 32;
    async16(&lds[d + sl0], g);
    async16(&lds[d + sl1], g + (size_t)128 * K_DIM);
  };

  // Prologue: stage ks0(0), ks1(0); retire ks0(0) (ks1(0) stays in flight).
  stageA(0, 0); stageB(0, 0);
  stageA(0, 1); stageB(0, 1);
  asm volatile("s_waitcnt vmcnt(4)" ::: "memory");
  __builtin_amdgcn_s_barrier();

  auto tile = [&](int t, bool st, int vm1, int vm3) {
    const int cb = (t & 1) * 16384;
    short8 af[4], bf[4];
    // ---- ph0: ks0, m0-3 ----
#pragma unroll
    for (int n = 0; n < 4; ++n) bf[n] = *(const short8*)&lds[32768 + cb + b_rd + n * 512];
#pragma unroll
    for (int m = 0; m < 4; ++m) af[m] = *(const short8*)&lds[cb + a_rd + m * 512];
    if (st) stageA(t + 1, 0);
    __builtin_amdgcn_s_barrier();
    asm volatile("s_waitcnt lgkmcnt(0)" ::: "memory");
    __builtin_amdgcn_sched_barrier(0);
    __builtin_amdgcn_s_setprio(1);
#pragma unroll
    for (int m = 0; m < 4; ++m)
#pragma unroll
      for (int n = 0; n < 4; ++n)
        acc[m][n] = __builtin_amdgcn_mfma_f32_16x16x32_bf16(af[m], bf[n], acc[m][n], 0, 0, 0);
    __builtin_amdgcn_s_setprio(0);
    __builtin_amdgcn_s_barrier();
    // ---- ph1: ks0, m4-7 (bf reused in regs) ----
#pragma unroll
    for (int m = 0; m < 4; ++m) af[m] = *(const short8*)&lds[cb + a_rd + (4 + m) * 512];
    if (st) stageB(t + 1, 0);
    __builtin_amdgcn_s_barrier();
    asm volatile("s_waitcnt lgkmcnt(0)" ::: "memory");
    __builtin_amdgcn_sched_barrier(0);
    __builtin_amdgcn_s_setprio(1);
#pragma unroll
    for (int m = 0; m < 4; ++m)
#pragma unroll
      for (int n = 0; n < 4; ++n)
        acc[4 + m][n] = __builtin_amdgcn_mfma_f32_16x16x32_bf16(af[m], bf[n], acc[4 + m][n], 0, 0, 0);
    __builtin_amdgcn_s_setprio(0);
    if (vm1 == 4) asm volatile("s_waitcnt vmcnt(4)" ::: "memory");
    else if (vm1 == 0) asm volatile("s_waitcnt vmcnt(0)" ::: "memory");
    __builtin_amdgcn_s_barrier();
    // ---- ph2: ks1, m0-3 ----
#pragma unroll
    for (int n = 0; n < 4; ++n) bf[n] = *(const short8*)&lds[32768 + cb + 8192 + b_rd + n * 512];
#pragma unroll
    for (int m = 0; m < 4; ++m) af[m] = *(const short8*)&lds[cb + 8192 + a_rd + m * 512];
    if (st) stageA(t + 1, 1);
    __builtin_amdgcn_s_barrier();
    asm volatile("s_waitcnt lgkmcnt(0)" ::: "memory");
    __builtin_amdgcn_sched_barrier(0);
    __builtin_amdgcn_s_setprio(1);
#pragma unroll
    for (int m = 0; m < 4; ++m)
#pragma unroll
      for (int n = 0; n < 4; ++n)
        acc[m][n] = __builtin_amdgcn_mfma_f32_16x16x32_bf16(af[m], bf[n], acc[m][n], 0, 0, 0);
    __builtin_amdgcn_s_setprio(0);
    __builtin_amdgcn_s_barrier();
    // ---- ph3: ks1, m4-7 ----
#pragma unroll
    for (int m = 0; m < 4; ++m) af[m] = *(const short8*)&lds[cb + 8192 + a_rd + (4 + m) * 512];
    if (st) stageB(t + 1, 1);
    __builtin_amdgcn_s_barrier();
    asm volatile("s_waitcnt lgkmcnt(0)" ::: "memory");
    __builtin_amdgcn_sched_barrier(0);
    __builtin_amdgcn_s_setprio(1);
#pragma unroll
    for (int m = 0; m < 4; ++m)
#pragma unroll
      for (int n = 0; n < 4; ++n)
        acc[4 + m][n] = __builtin_amdgcn_mfma_f32_16x16x32_bf16(af[m], bf[n], acc[4 + m][n], 0, 0, 0);
    __builtin_amdgcn_s_setprio(0);
    if (vm3 == 4) asm volatile("s_waitcnt vmcnt(4)" ::: "memory");
    else if (vm3 == 0) asm volatile("s_waitcnt vmcnt(0)" ::: "memory");
    __builtin_amdgcn_s_barrier();
  };

  // 32 K-tiles of 64. Tiles 0..30 stage tile t+1; tile 31 drains.
#pragma unroll 1
  for (int t = 0; t < 31; ++t) tile(t, true, 4, 4);
  tile(31, false, 0, -1);

  // Epilogue: C/D layout col = lane&15, row = quad*4 + reg  [m89-verified]
  float* op = out + (size_t)(m0 + wm * 128 + quad * 4) * N_DIM + n0 + wn * 64 + l15;
#pragma unroll
  for (int mi = 0; mi < 8; ++mi)
#pragma unroll
    for (int r = 0; r < 4; ++r)
#pragma unroll
      for (int ni = 0; ni < 4; ++ni)
        op[(size_t)(mi * 16 + r) * N_DIM + ni * 16] = acc[mi][ni][r];
}

// -----------------------------------------------------------------------------
extern "C" void kernel_launch(void* const* d_in, const int* in_sizes, int n_in,
                              void* d_out, int out_size, void* d_ws, size_t ws_size,
                              hipStream_t stream) {
  const float* x      = (const float*)d_in[0];  // [4,2048,2048] fp32
  const int*   packed = (const int*)d_in[1];    // [5767168] int32 (byte values)
  const float* scales = (const float*)d_in[2];  // [90112]
  const float* zeros  = (const float*)d_in[3];  // [90112]
  const float* lA     = (const float*)d_in[4];  // [2048,16]
  const float* lB     = (const float*)d_in[5];  // [16,5632]
  float* out = (float*)d_out;                   // [4,2048,5632] fp32

  short* xb = (short*)d_ws;                     // x in bf16: 16,777,216 shorts
  short* wb = xb + (size_t)M_DIM * K_DIM;       // W' in bf16: 11,534,336 shorts
  // lAT scratch lives in the TAIL of out; dequant consumes it before gemm
  // overwrites every element of out.
  float* lAT = out + ((size_t)4 * 2048 * N_DIM - 16 * K_DIM);

  cvt_x_kernel<<<(M_DIM * K_DIM) / (256 * 4), 256, 0, stream>>>(x, xb);
  lat_kernel<<<K_DIM / 256, 256, 0, stream>>>(lA, lAT);
  dequant_lora_kernel<<<N_DIM, 256, 0, stream>>>(packed, scales, zeros, lAT, lB, wb);
  gemm_kernel<<<dim3(N_DIM / 256 * (M_DIM / 256)), 512, 0, stream>>>(xb, wb, out);
}

// Round 6
// 465.017 us; speedup vs baseline: 1.0028x; 1.0028x over previous
//
#include <hip/hip_runtime.h>

#define M_DIM 8192
#define K_DIM 2048
#define N_DIM 5632

typedef __attribute__((ext_vector_type(8))) short short8;
typedef __attribute__((ext_vector_type(4))) short s4v;
typedef __attribute__((ext_vector_type(4))) float f32x4;

// fp32 -> bf16 round-to-nearest-even (bit trick; inputs are finite)
__device__ __forceinline__ short f2b(float f) {
  union { float f; unsigned u; } v; v.f = f;
  unsigned r = v.u + 0x7FFFu + ((v.u >> 16) & 1u);
  return (short)(r >> 16);
}

// async global->LDS, 16B per lane. LDS dest must be wave-uniform base + lane*16.
__device__ __forceinline__ void async16(void* lds, const void* g) {
  __builtin_amdgcn_global_load_lds(
      (const __attribute__((address_space(1))) unsigned*)g,
      (__attribute__((address_space(3))) unsigned*)lds,
      16, 0, 0);
}

// ---------------- Kernel 1: x fp32 -> bf16 (fully coalesced) -----------------
__global__ __launch_bounds__(256) void cvt_x_kernel(const float* __restrict__ x,
                                                    short* __restrict__ xb) {
  long t = (long)blockIdx.x * 256 + threadIdx.x;   // 4 elements per thread
  float4 f = ((const float4*)x)[t];
  s4v o;
  o[0] = f2b(f.x); o[1] = f2b(f.y); o[2] = f2b(f.z); o[3] = f2b(f.w);
  *(s4v*)(xb + 4 * t) = o;
}

// ---------------- Kernel 1b: transpose lA -> lAT[16][2048], fold 2x scale ----
__global__ __launch_bounds__(256) void lat_kernel(const float* __restrict__ lA,
                                                  float* __restrict__ lAT) {
  int i = blockIdx.x * 256 + threadIdx.x;          // 8 blocks x 256 = 2048
  const float4* row = (const float4*)(lA + (size_t)i * 16);
  float4 v0 = row[0], v1 = row[1], v2 = row[2], v3 = row[3];
  float vals[16] = {v0.x, v0.y, v0.z, v0.w, v1.x, v1.y, v1.z, v1.w,
                    v2.x, v2.y, v2.z, v2.w, v3.x, v3.y, v3.z, v3.w};
#pragma unroll
  for (int r = 0; r < 16; ++r) lAT[r * K_DIM + i] = vals[r] * 2.0f;
}

// ---------------- Kernel 2: dequant int4 + fold rank-16 LoRA into W' ---------
// W'[o][i] = (q - zero[g]) * scale[g] + sum_r lAT[r][i] * lB[r][o]
__global__ __launch_bounds__(256) void dequant_lora_kernel(
    const int* __restrict__ packed, const float* __restrict__ scales,
    const float* __restrict__ zeros, const float* __restrict__ lAT,
    const float* __restrict__ lB, short* __restrict__ wb) {
  int o = blockIdx.x;
  int i0 = threadIdx.x * 8;
  long e0 = (long)o * K_DIM + i0;
  int4 p = ((const int4*)packed)[e0 >> 3];
  int g = (int)(e0 >> 7);
  float s = scales[g], z = zeros[g];

  float accv[8];
#pragma unroll
  for (int d = 0; d < 4; ++d) {
    int pv = (&p.x)[d];
    accv[2 * d]     = ((float)(pv & 0xF) - z) * s;
    accv[2 * d + 1] = ((float)((pv >> 4) & 0xF) - z) * s;
  }
#pragma unroll
  for (int r = 0; r < 16; ++r) {
    float b = lB[r * N_DIM + o];             // uniform per block -> scalar load
    const float4* ar = (const float4*)&lAT[r * K_DIM + i0];
    float4 a0 = ar[0], a1 = ar[1];
    accv[0] += a0.x * b; accv[1] += a0.y * b;
    accv[2] += a0.z * b; accv[3] += a0.w * b;
    accv[4] += a1.x * b; accv[5] += a1.y * b;
    accv[6] += a1.z * b; accv[7] += a1.w * b;
  }
  short8 out8;
#pragma unroll
  for (int j = 0; j < 8; ++j) out8[j] = f2b(accv[j]);
  *(short8*)(wb + e0) = out8;
}

// ---------------- Kernel 3: C[m][n] = sum_k X[m][k] * W'[n][k] ---------------
// m201-template port, R6: R5 schedule + the R1-R4 proven-0-conflict XOR
// swizzle (R5 measured 1.73e7 bank conflicts ~= 8 extra cyc/ds_read: row
// stride 64B = 16 banks, unswizzled rows alias every 2 rows).
// Layout: A bufs [0,32768), B bufs [32768,65536) shorts; buf c at +c*16384;
// ks slice s at +s*8192; region = 256 rows x 4 chunks(16B). SWIZZLE: LDS slot
// sl of row r holds global chunk sl ^ ((r>>1)&3)  [involution; rule #21:
// linear LDS dest + inverse-swizzled global source + swizzled read].
// Reads: rswz = quad ^ ((l15>>1)&3); fragment-row bases are multiples of 16
// so (row>>1)&3 == (l15>>1)&3 for all fragments. Measured 0 conflicts R1-R4.
// Phase = {ds_reads; stage; BAR; lgkmcnt(0); setprio(1); 16 MFMA; setprio(0);
// [vmcnt]; BAR}: the 16-MFMA cluster (~620 cyc backlog/SIMD) drains ACROSS
// the barrier, hiding the next phase's lgkm-wait + LDS burst.
// Per-tile pipes (conflict-free): LDS 2304 cyc vs MFMA 2480 cyc -- balanced.
// 4 phases/K-tile: ph0 m0-3/ks0, ph1 m4-7/ks0, ph2 m0-3/ks1, ph3 m4-7/ks1.
// Stage of tile t+1: ph0 A-ks0, ph1 B-ks0, ph2 A-ks1, ph3 B-ks1.
// vmcnt(4) at end-ph1 (retires ks1(t)) and end-ph3 (retires ks0(t+1)).
// Hazards (audited R5): stage into buf (t+1)&1 issues after end-of-(t-1)
// barrier where all its reads were consumed; reads gated by vmcnt+BAR.
__global__ __launch_bounds__(512, 2) void gemm_kernel(const short* __restrict__ xb,
                                                      const short* __restrict__ wb,
                                                      float* __restrict__ out) {
  __shared__ __align__(16) short lds[65536];   // 128 KB

  const int tid = threadIdx.x;
  const int lane = tid & 63;
  const int wave = tid >> 6;
  const int wm = wave >> 2, wn = wave & 3;     // 2(M) x 4(N) wave grid
  const int l15 = lane & 15, quad = lane >> 4;

  // XCD-aware bijective swizzle: 704 blocks = 8 XCDs x 88
  int flat = blockIdx.x;
  int swz = (flat & 7) * 88 + (flat >> 3);
  int bm = swz / 22, bn_ = swz - bm * 22;
  const int m0 = bm * 256, n0 = bn_ * 256;

  const short* a_base = xb + (size_t)m0 * K_DIM;
  const short* b_base = wb + (size_t)n0 * K_DIM;

  // ds_read offsets (shorts) within a ks region; swizzled chunk slot.
  const int rswz = quad ^ ((l15 >> 1) & 3);
  const int a_rd = (wm * 128 + l15) * 32 + rswz * 8;   // + m*512
  const int b_rd = (wn * 64 + l15) * 32 + rswz * 8;    // + n*512

  // Staging: thread stages LDS chunks i=tid and i=512+tid (row i>>2, slot
  // i&3). Linear LDS dest; global source chunk = slot ^ ((row>>1)&3).
  // Row+128 has the same xor term (128>>1 = 64, 64&3 == 0).
  const int srow = tid >> 2;
  const int schunk = (tid & 3) ^ ((srow >> 1) & 3);
  const short* ag0 = a_base + (size_t)srow * K_DIM + schunk * 8;
  const short* bg0 = b_base + (size_t)srow * K_DIM + schunk * 8;
  const int sl0 = tid * 8, sl1 = (512 + tid) * 8;

  f32x4 acc[8][4] = {};

  // stage A or B k-slice s of K-tile t into buf (t&1)
  auto stageA = [&](int t, int s) {
    const int d = (t & 1) * 16384 + s * 8192;
    const short* g = ag0 + t * 64 + s * 32;
    async16(&lds[d + sl0], g);
    async16(&lds[d + sl1], g + (size_t)128 * K_DIM);
  };
  auto stageB = [&](int t, int s) {
    const int d = 32768 + (t & 1) * 16384 + s * 8192;
    const short* g = bg0 + t * 64 + s * 32;
    async16(&lds[d + sl0], g);
    async16(&lds[d + sl1], g + (size_t)128 * K_DIM);
  };

  // Prologue: stage ks0(0), ks1(0); retire ks0(0) (ks1(0) stays in flight).
  stageA(0, 0); stageB(0, 0);
  stageA(0, 1); stageB(0, 1);
  asm volatile("s_waitcnt vmcnt(4)" ::: "memory");
  __builtin_amdgcn_s_barrier();

  auto tile = [&](int t, bool st, int vm1, int vm3) {
    const int cb = (t & 1) * 16384;
    short8 af[4], bf[4];
    // ---- ph0: ks0, m0-3 ----
#pragma unroll
    for (int n = 0; n < 4; ++n) bf[n] = *(const short8*)&lds[32768 + cb + b_rd + n * 512];
#pragma unroll
    for (int m = 0; m < 4; ++m) af[m] = *(const short8*)&lds[cb + a_rd + m * 512];
    if (st) stageA(t + 1, 0);
    __builtin_amdgcn_s_barrier();
    asm volatile("s_waitcnt lgkmcnt(0)" ::: "memory");
    __builtin_amdgcn_sched_barrier(0);
    __builtin_amdgcn_s_setprio(1);
#pragma unroll
    for (int m = 0; m < 4; ++m)
#pragma unroll
      for (int n = 0; n < 4; ++n)
        acc[m][n] = __builtin_amdgcn_mfma_f32_16x16x32_bf16(af[m], bf[n], acc[m][n], 0, 0, 0);
    __builtin_amdgcn_s_setprio(0);
    __builtin_amdgcn_s_barrier();
    // ---- ph1: ks0, m4-7 (bf reused in regs) ----
#pragma unroll
    for (int m = 0; m < 4; ++m) af[m] = *(const short8*)&lds[cb + a_rd + (4 + m) * 512];
    if (st) stageB(t + 1, 0);
    __builtin_amdgcn_s_barrier();
    asm volatile("s_waitcnt lgkmcnt(0)" ::: "memory");
    __builtin_amdgcn_sched_barrier(0);
    __builtin_amdgcn_s_setprio(1);
#pragma unroll
    for (int m = 0; m < 4; ++m)
#pragma unroll
      for (int n = 0; n < 4; ++n)
        acc[4 + m][n] = __builtin_amdgcn_mfma_f32_16x16x32_bf16(af[m], bf[n], acc[4 + m][n], 0, 0, 0);
    __builtin_amdgcn_s_setprio(0);
    if (vm1 == 4) asm volatile("s_waitcnt vmcnt(4)" ::: "memory");
    else if (vm1 == 0) asm volatile("s_waitcnt vmcnt(0)" ::: "memory");
    __builtin_amdgcn_s_barrier();
    // ---- ph2: ks1, m0-3 ----
#pragma unroll
    for (int n = 0; n < 4; ++n) bf[n] = *(const short8*)&lds[32768 + cb + 8192 + b_rd + n * 512];
#pragma unroll
    for (int m = 0; m < 4; ++m) af[m] = *(const short8*)&lds[cb + 8192 + a_rd + m * 512];
    if (st) stageA(t + 1, 1);
    __builtin_amdgcn_s_barrier();
    asm volatile("s_waitcnt lgkmcnt(0)" ::: "memory");
    __builtin_amdgcn_sched_barrier(0);
    __builtin_amdgcn_s_setprio(1);
#pragma unroll
    for (int m = 0; m < 4; ++m)
#pragma unroll
      for (int n = 0; n < 4; ++n)
        acc[m][n] = __builtin_amdgcn_mfma_f32_16x16x32_bf16(af[m], bf[n], acc[m][n], 0, 0, 0);
    __builtin_amdgcn_s_setprio(0);
    __builtin_amdgcn_s_barrier();
    // ---- ph3: ks1, m4-7 ----
#pragma unroll
    for (int m = 0; m < 4; ++m) af[m] = *(const short8*)&lds[cb + 8192 + a_rd + (4 + m) * 512];
    if (st) stageB(t + 1, 1);
    __builtin_amdgcn_s_barrier();
    asm volatile("s_waitcnt lgkmcnt(0)" ::: "memory");
    __builtin_amdgcn_sched_barrier(0);
    __builtin_amdgcn_s_setprio(1);
#pragma unroll
    for (int m = 0; m < 4; ++m)
#pragma unroll
      for (int n = 0; n < 4; ++n)
        acc[4 + m][n] = __builtin_amdgcn_mfma_f32_16x16x32_bf16(af[m], bf[n], acc[4 + m][n], 0, 0, 0);
    __builtin_amdgcn_s_setprio(0);
    if (vm3 == 4) asm volatile("s_waitcnt vmcnt(4)" ::: "memory");
    else if (vm3 == 0) asm volatile("s_waitcnt vmcnt(0)" ::: "memory");
    __builtin_amdgcn_s_barrier();
  };

  // 32 K-tiles of 64. Tiles 0..30 stage tile t+1; tile 31 drains.
#pragma unroll 1
  for (int t = 0; t < 31; ++t) tile(t, true, 4, 4);
  tile(31, false, 0, -1);

  // Epilogue: C/D layout col = lane&15, row = quad*4 + reg  [m89-verified]
  float* op = out + (size_t)(m0 + wm * 128 + quad * 4) * N_DIM + n0 + wn * 64 + l15;
#pragma unroll
  for (int mi = 0; mi < 8; ++mi)
#pragma unroll
    for (int r = 0; r < 4; ++r)
#pragma unroll
      for (int ni = 0; ni < 4; ++ni)
        op[(size_t)(mi * 16 + r) * N_DIM + ni * 16] = acc[mi][ni][r];
}

// -----------------------------------------------------------------------------
extern "C" void kernel_launch(void* const* d_in, const int* in_sizes, int n_in,
                              void* d_out, int out_size, void* d_ws, size_t ws_size,
                              hipStream_t stream) {
  const float* x      = (const float*)d_in[0];  // [4,2048,2048] fp32
  const int*   packed = (const int*)d_in[1];    // [5767168] int32 (byte values)
  const float* scales = (const float*)d_in[2];  // [90112]
  const float* zeros  = (const float*)d_in[3];  // [90112]
  const float* lA     = (const float*)d_in[4];  // [2048,16]
  const float* lB     = (const float*)d_in[5];  // [16,5632]
  float* out = (float*)d_out;                   // [4,2048,5632] fp32

  short* xb = (short*)d_ws;                     // x in bf16: 16,777,216 shorts
  short* wb = xb + (size_t)M_DIM * K_DIM;       // W' in bf16: 11,534,336 shorts
  // lAT scratch lives in the TAIL of out; dequant consumes it before gemm
  // overwrites every element of out.
  float* lAT = out + ((size_t)4 * 2048 * N_DIM - 16 * K_DIM);

  cvt_x_kernel<<<(M_DIM * K_DIM) / (256 * 4), 256, 0, stream>>>(x, xb);
  lat_kernel<<<K_DIM / 256, 256, 0, stream>>>(lA, lAT);
  dequant_lora_kernel<<<N_DIM, 256, 0, stream>>>(packed, scales, zeros, lAT, lB, wb);
  gemm_kernel<<<dim3(N_DIM / 256 * (M_DIM / 256)), 512, 0, stream>>>(xb, wb, out);
}

// Round 7
// 452.678 us; speedup vs baseline: 1.0301x; 1.0273x over previous
//
#include <hip/hip_runtime.h>

#define M_DIM 8192
#define K_DIM 2048
#define N_DIM 5632

typedef __attribute__((ext_vector_type(8))) short short8;
typedef __attribute__((ext_vector_type(4))) short s4v;
typedef __attribute__((ext_vector_type(4))) float f32x4;

// fp32 -> bf16 round-to-nearest-even (bit trick; inputs are finite)
__device__ __forceinline__ short f2b(float f) {
  union { float f; unsigned u; } v; v.f = f;
  unsigned r = v.u + 0x7FFFu + ((v.u >> 16) & 1u);
  return (short)(r >> 16);
}

// async global->LDS, 16B per lane. LDS dest must be wave-uniform base + lane*16.
__device__ __forceinline__ void async16(void* lds, const void* g) {
  __builtin_amdgcn_global_load_lds(
      (const __attribute__((address_space(1))) unsigned*)g,
      (__attribute__((address_space(3))) unsigned*)lds,
      16, 0, 0);
}

// ---------------- Kernel 1: x fp32 -> bf16 (fully coalesced) -----------------
__global__ __launch_bounds__(256) void cvt_x_kernel(const float* __restrict__ x,
                                                    short* __restrict__ xb) {
  long t = (long)blockIdx.x * 256 + threadIdx.x;   // 4 elements per thread
  float4 f = ((const float4*)x)[t];
  s4v o;
  o[0] = f2b(f.x); o[1] = f2b(f.y); o[2] = f2b(f.z); o[3] = f2b(f.w);
  *(s4v*)(xb + 4 * t) = o;
}

// ---------------- Kernel 1b: transpose lA -> lAT[16][2048], fold 2x scale ----
__global__ __launch_bounds__(256) void lat_kernel(const float* __restrict__ lA,
                                                  float* __restrict__ lAT) {
  int i = blockIdx.x * 256 + threadIdx.x;          // 8 blocks x 256 = 2048
  const float4* row = (const float4*)(lA + (size_t)i * 16);
  float4 v0 = row[0], v1 = row[1], v2 = row[2], v3 = row[3];
  float vals[16] = {v0.x, v0.y, v0.z, v0.w, v1.x, v1.y, v1.z, v1.w,
                    v2.x, v2.y, v2.z, v2.w, v3.x, v3.y, v3.z, v3.w};
#pragma unroll
  for (int r = 0; r < 16; ++r) lAT[r * K_DIM + i] = vals[r] * 2.0f;
}

// ---------------- Kernel 2: dequant int4 + fold rank-16 LoRA into W' ---------
// W'[o][i] = (q - zero[g]) * scale[g] + sum_r lAT[r][i] * lB[r][o]
__global__ __launch_bounds__(256) void dequant_lora_kernel(
    const int* __restrict__ packed, const float* __restrict__ scales,
    const float* __restrict__ zeros, const float* __restrict__ lAT,
    const float* __restrict__ lB, short* __restrict__ wb) {
  int o = blockIdx.x;
  int i0 = threadIdx.x * 8;
  long e0 = (long)o * K_DIM + i0;
  int4 p = ((const int4*)packed)[e0 >> 3];
  int g = (int)(e0 >> 7);
  float s = scales[g], z = zeros[g];

  float accv[8];
#pragma unroll
  for (int d = 0; d < 4; ++d) {
    int pv = (&p.x)[d];
    accv[2 * d]     = ((float)(pv & 0xF) - z) * s;
    accv[2 * d + 1] = ((float)((pv >> 4) & 0xF) - z) * s;
  }
#pragma unroll
  for (int r = 0; r < 16; ++r) {
    float b = lB[r * N_DIM + o];             // uniform per block -> scalar load
    const float4* ar = (const float4*)&lAT[r * K_DIM + i0];
    float4 a0 = ar[0], a1 = ar[1];
    accv[0] += a0.x * b; accv[1] += a0.y * b;
    accv[2] += a0.z * b; accv[3] += a0.w * b;
    accv[4] += a1.x * b; accv[5] += a1.y * b;
    accv[6] += a1.z * b; accv[7] += a1.w * b;
  }
  short8 out8;
#pragma unroll
  for (int j = 0; j < 8; ++j) out8[j] = f2b(accv[j]);
  *(short8*)(wb + e0) = out8;
}

// ---------------- Kernel 3: C[m][n] = sum_k X[m][k] * W'[n][k] ---------------
// R7: counted-lgkm FRAGMENT PIPELINE on the R6 layout (layout/swizzle/staging
// identical to R6, which measured 0 bank conflicts).
// R6 model (validated): per phase, reads->BAR->lgkmcnt(0)->MFMA serializes
// LDS drain (~770cyc/CU) and MFMA (~620cyc/CU) because the wait covers reads
// issued THE SAME phase; tile = 4x1390 = 5560 cyc ~= measured 5427.
// Fix: reads issued in phase p feed phase p+1's MFMA; pre-MFMA wait is
// COUNTED to exclude this phase's reads (lgkmcnt(4/8/4/8) = exactly the new
// read count; all loop lgkm ops are DS, which retire in-order). Reads drain
// under the 620-cyc MFMA issue -> both pipes busy.
// Fragment ping-pong: afX/afY alternate per phase, bfP/bfQ per 2 phases:
//   ph0: rd afY=ks0 m4-7;            mfma acc[0-3] (afX,bfP)   [ks0 m0-3]
//   ph1: rd bfQ=ks1 B, afX=ks1 m0-3; mfma acc[4-7] (afY,bfP)   [ks0 m4-7]
//   ph2: rd afY=ks1 m4-7;            mfma acc[0-3] (afX,bfQ)   [ks1 m0-3]
//   ph3: rd bfP=ks0' B, afX=ks0'm0-3;mfma acc[4-7] (afY,bfQ)   [ks1 m4-7]
// (per-acc accumulation order unchanged vs R6: ks0 then ks1, tiles ascending)
// Sync: TWO barriers/tile (end-ph0, end-ph2), each preceded by counted
// vmcnt(2) that retires the k-slice needed by the phase after the barrier
// (its 2 stages were issued 2-3 phases earlier; the 2 newest may fly on).
// Hazard audit: barrier spacing bounds skew <1 tile; every stage-vs-read WAR
// has >=2 phases + 1 barrier slack; every DMA->read RAW is gated by each
// wave's OWN vmcnt BEFORE the shared barrier (so at release, all waves'
// stages are retired). t=31: vmcnt(0) at end-ph0; ph3 reads skipped.
// Regs: afX/afY/bfP/bfQ = 64 VGPR + acc 128 -> ~252 total (2-wave budget 256).
__global__ __launch_bounds__(512, 2) void gemm_kernel(const short* __restrict__ xb,
                                                      const short* __restrict__ wb,
                                                      float* __restrict__ out) {
  __shared__ __align__(16) short lds[65536];   // 128 KB

  const int tid = threadIdx.x;
  const int lane = tid & 63;
  const int wave = tid >> 6;
  const int wm = wave >> 2, wn = wave & 3;     // 2(M) x 4(N) wave grid
  const int l15 = lane & 15, quad = lane >> 4;

  // XCD-aware bijective swizzle: 704 blocks = 8 XCDs x 88
  int flat = blockIdx.x;
  int swz = (flat & 7) * 88 + (flat >> 3);
  int bm = swz / 22, bn_ = swz - bm * 22;
  const int m0 = bm * 256, n0 = bn_ * 256;

  const short* a_base = xb + (size_t)m0 * K_DIM;
  const short* b_base = wb + (size_t)n0 * K_DIM;

  // ds_read offsets (shorts) within a ks region; swizzled chunk slot.
  // Swizzle: LDS slot sl of row r holds global chunk sl ^ ((r>>1)&3).
  const int rswz = quad ^ ((l15 >> 1) & 3);
  const int a_rd = (wm * 128 + l15) * 32 + rswz * 8;   // + m*512
  const int b_rd = (wn * 64 + l15) * 32 + rswz * 8;    // + n*512

  // Staging: linear LDS dest; inverse-swizzled global source chunk.
  const int srow = tid >> 2;
  const int schunk = (tid & 3) ^ ((srow >> 1) & 3);
  const short* ag0 = a_base + (size_t)srow * K_DIM + schunk * 8;
  const short* bg0 = b_base + (size_t)srow * K_DIM + schunk * 8;
  const int sl0 = tid * 8, sl1 = (512 + tid) * 8;

  f32x4 acc[8][4] = {};
  short8 afX[4], afY[4], bfP[4], bfQ[4];

  // stage A or B k-slice s of K-tile t into buf (t&1)
  auto stageA = [&](int t, int s) {
    const int d = (t & 1) * 16384 + s * 8192;
    const short* g = ag0 + t * 64 + s * 32;
    async16(&lds[d + sl0], g);
    async16(&lds[d + sl1], g + (size_t)128 * K_DIM);
  };
  auto stageB = [&](int t, int s) {
    const int d = 32768 + (t & 1) * 16384 + s * 8192;
    const short* g = bg0 + t * 64 + s * 32;
    async16(&lds[d + sl0], g);
    async16(&lds[d + sl1], g + (size_t)128 * K_DIM);
  };
  auto mm4 = [&](int base, short8* a4, short8* b4) {
#pragma unroll
    for (int m = 0; m < 4; ++m)
#pragma unroll
      for (int n = 0; n < 4; ++n)
        acc[base + m][n] = __builtin_amdgcn_mfma_f32_16x16x32_bf16(
            a4[m], b4[n], acc[base + m][n], 0, 0, 0);
  };

  // Prologue: stage tile 0 (ks0 then ks1); retire ks0; prime ph0 fragments.
  stageA(0, 0); stageB(0, 0);
  stageA(0, 1); stageB(0, 1);
  asm volatile("s_waitcnt vmcnt(4)" ::: "memory");
  __builtin_amdgcn_s_barrier();
#pragma unroll
  for (int n = 0; n < 4; ++n) bfP[n] = *(const short8*)&lds[32768 + b_rd + n * 512];
#pragma unroll
  for (int m = 0; m < 4; ++m) afX[m] = *(const short8*)&lds[a_rd + m * 512];

#pragma unroll 1
  for (int t = 0; t < 32; ++t) {
    const int cb = (t & 1) * 16384;
    const int nb = ((t + 1) & 1) * 16384;
    const bool st = (t < 31);
    // ---- ph0: rd afY (ks0 m4-7); stage A-ks0(t+1); mfma ks0 m0-3 ----
#pragma unroll
    for (int m = 0; m < 4; ++m) afY[m] = *(const short8*)&lds[cb + a_rd + (4 + m) * 512];
    if (st) stageA(t + 1, 0);
    asm volatile("s_waitcnt lgkmcnt(4)" ::: "memory");  // prev-phase reads done
    __builtin_amdgcn_sched_barrier(0);
    __builtin_amdgcn_s_setprio(1);
    mm4(0, afX, bfP);
    __builtin_amdgcn_s_setprio(0);
    if (st) asm volatile("s_waitcnt vmcnt(2)" ::: "memory");  // ks1(t) resident
    else    asm volatile("s_waitcnt vmcnt(0)" ::: "memory");
    __builtin_amdgcn_s_barrier();
    // ---- ph1: rd bfQ (ks1 B) + afX (ks1 m0-3); stage B-ks0(t+1);
    //          mfma ks0 m4-7 ----
#pragma unroll
    for (int n = 0; n < 4; ++n) bfQ[n] = *(const short8*)&lds[32768 + cb + 8192 + b_rd + n * 512];
#pragma unroll
    for (int m = 0; m < 4; ++m) afX[m] = *(const short8*)&lds[cb + 8192 + a_rd + m * 512];
    if (st) stageB(t + 1, 0);
    asm volatile("s_waitcnt lgkmcnt(8)" ::: "memory");  // afY done; 8 new fly
    __builtin_amdgcn_sched_barrier(0);
    __builtin_amdgcn_s_setprio(1);
    mm4(4, afY, bfP);
    __builtin_amdgcn_s_setprio(0);
    // ---- ph2: rd afY (ks1 m4-7); stage A-ks1(t+1); mfma ks1 m0-3 ----
#pragma unroll
    for (int m = 0; m < 4; ++m) afY[m] = *(const short8*)&lds[cb + 8192 + a_rd + (4 + m) * 512];
    if (st) stageA(t + 1, 1);
    asm volatile("s_waitcnt lgkmcnt(4)" ::: "memory");  // bfQ,afX done
    __builtin_amdgcn_sched_barrier(0);
    __builtin_amdgcn_s_setprio(1);
    mm4(0, afX, bfQ);
    __builtin_amdgcn_s_setprio(0);
    if (st) asm volatile("s_waitcnt vmcnt(2)" ::: "memory");  // ks0(t+1) resident
    __builtin_amdgcn_s_barrier();
    // ---- ph3: rd bfP (ks0' B) + afX (ks0' m0-3); stage B-ks1(t+1);
    //          mfma ks1 m4-7 ----
    if (st) {
#pragma unroll
      for (int n = 0; n < 4; ++n) bfP[n] = *(const short8*)&lds[32768 + nb + b_rd + n * 512];
#pragma unroll
      for (int m = 0; m < 4; ++m) afX[m] = *(const short8*)&lds[nb + a_rd + m * 512];
      stageB(t + 1, 1);
      asm volatile("s_waitcnt lgkmcnt(8)" ::: "memory");  // afY done; 8 new fly
    } else {
      asm volatile("s_waitcnt lgkmcnt(0)" ::: "memory");
    }
    __builtin_amdgcn_sched_barrier(0);
    __builtin_amdgcn_s_setprio(1);
    mm4(4, afY, bfQ);
    __builtin_amdgcn_s_setprio(0);
  }

  // Epilogue: C/D layout col = lane&15, row = quad*4 + reg  [m89-verified]
  float* op = out + (size_t)(m0 + wm * 128 + quad * 4) * N_DIM + n0 + wn * 64 + l15;
#pragma unroll
  for (int mi = 0; mi < 8; ++mi)
#pragma unroll
    for (int r = 0; r < 4; ++r)
#pragma unroll
      for (int ni = 0; ni < 4; ++ni)
        op[(size_t)(mi * 16 + r) * N_DIM + ni * 16] = acc[mi][ni][r];
}

// -----------------------------------------------------------------------------
extern "C" void kernel_launch(void* const* d_in, const int* in_sizes, int n_in,
                              void* d_out, int out_size, void* d_ws, size_t ws_size,
                              hipStream_t stream) {
  const float* x      = (const float*)d_in[0];  // [4,2048,2048] fp32
  const int*   packed = (const int*)d_in[1];    // [5767168] int32 (byte values)
  const float* scales = (const float*)d_in[2];  // [90112]
  const float* zeros  = (const float*)d_in[3];  // [90112]
  const float* lA     = (const float*)d_in[4];  // [2048,16]
  const float* lB     = (const float*)d_in[5];  // [16,5632]
  float* out = (float*)d_out;                   // [4,2048,5632] fp32

  short* xb = (short*)d_ws;                     // x in bf16: 16,777,216 shorts
  short* wb = xb + (size_t)M_DIM * K_DIM;       // W' in bf16: 11,534,336 shorts
  // lAT scratch lives in the TAIL of out; dequant consumes it before gemm
  // overwrites every element of out.
  float* lAT = out + ((size_t)4 * 2048 * N_DIM - 16 * K_DIM);

  cvt_x_kernel<<<(M_DIM * K_DIM) / (256 * 4), 256, 0, stream>>>(x, xb);
  lat_kernel<<<K_DIM / 256, 256, 0, stream>>>(lA, lAT);
  dequant_lora_kernel<<<N_DIM, 256, 0, stream>>>(packed, scales, zeros, lAT, lB, wb);
  gemm_kernel<<<dim3(N_DIM / 256 * (M_DIM / 256)), 512, 0, stream>>>(xb, wb, out);
}